// Round 7
// baseline (103.917 us; speedup 1.0000x reference)
//
#include <hip/hip_runtime.h>
#include <math.h>

typedef __attribute__((ext_vector_type(8))) short short8;
typedef __attribute__((ext_vector_type(4))) float f32x4;

#define SEQ 2048
#define NB  32

__device__ __forceinline__ unsigned short f2bf(float f) {
    unsigned u = __float_as_uint(f);
    u = (u + 0x7FFFu + ((u >> 16) & 1u)) >> 16;   // RNE
    return (unsigned short)u;
}

// async global->LDS, 16B per lane; LDS dest = wave-uniform base + lane*16
__device__ __forceinline__ void gload16(const unsigned short* g, unsigned short* l) {
    __builtin_amdgcn_global_load_lds(
        (__attribute__((address_space(1))) void*)(void*)(g),
        (__attribute__((address_space(3))) void*)(l), 16, 0, 0);
}

// ---------------------------------------------------------------------------
// fp32 -> bf16 (RNE), 8 elems/thread, grid-stride
// ---------------------------------------------------------------------------
__global__ __launch_bounds__(256) void cvt_bf16(const float* __restrict__ in,
                                                unsigned short* __restrict__ out, int n8) {
    int i = blockIdx.x * 256 + threadIdx.x;
    const int stride = gridDim.x * 256;
    for (; i < n8; i += stride) {
        const float4 a = ((const float4*)in)[i * 2];
        const float4 b = ((const float4*)in)[i * 2 + 1];
        uint4 o;
        o.x = f2bf(a.x) | ((unsigned)f2bf(a.y) << 16);
        o.y = f2bf(a.z) | ((unsigned)f2bf(a.w) << 16);
        o.z = f2bf(b.x) | ((unsigned)f2bf(b.y) << 16);
        o.w = f2bf(b.z) | ((unsigned)f2bf(b.w) << 16);
        ((uint4*)out)[i] = o;
    }
}

// 4 weight matrices in one dispatch (blockIdx.y selects)
__global__ __launch_bounds__(256) void cvt_w4(const float* __restrict__ w0,
                                              const float* __restrict__ w1,
                                              const float* __restrict__ w2,
                                              const float* __restrict__ w3,
                                              unsigned short* __restrict__ o0,
                                              unsigned short* __restrict__ o1,
                                              unsigned short* __restrict__ o2,
                                              unsigned short* __restrict__ o3) {
    const int which = blockIdx.y;
    const float* in = (which == 0) ? w0 : (which == 1) ? w1 : (which == 2) ? w2 : w3;
    unsigned short* out = (which == 0) ? o0 : (which == 1) ? o1 : (which == 2) ? o2 : o3;
    int i = blockIdx.x * 256 + threadIdx.x;
    const int stride = gridDim.x * 256;
    for (; i < 131072; i += stride) {
        const float4 a = ((const float4*)in)[i * 2];
        const float4 b = ((const float4*)in)[i * 2 + 1];
        uint4 o;
        o.x = f2bf(a.x) | ((unsigned)f2bf(a.y) << 16);
        o.y = f2bf(a.z) | ((unsigned)f2bf(a.w) << 16);
        o.z = f2bf(b.x) | ((unsigned)f2bf(b.y) << 16);
        o.w = f2bf(b.z) | ((unsigned)f2bf(b.w) << 16);
        ((uint4*)out)[i] = o;
    }
}

// ---------------------------------------------------------------------------
// bf16 MFMA GEMM: C[M,1024] = A[M,1024] @ W[1024,1024]^T + bias, M=4096.
// BM=128, BK=32, 256 thr. global_load_lds staging, DOUBLE-BUFFERED LDS:
//   prologue: STAGE(buf0); sync
//   loop:     STAGE(buf^1, t+1); ds_read+MFMA(buf); sync(vmcnt0 drain)
// (T3-minimum 2-phase: load latency hides under the MFMA cluster; the
//  round-6 single-buffer version drained vmcnt(0) BEFORE compute = 20% stall)
// BN=128: 4 waves 2x2 (64x64 each), grid.x = 8*nW, which=bx>>3 (QKV fused).
// BN=64:  4 waves 4x1 (32x64 each), grid.x = 16, which=0 (O projection).
// NOTE (round-3 lesson): head split is a .view — head h = GEMM ROWS
// h*128..h*128+127 per batch, NOT column slices.
// ---------------------------------------------------------------------------
template <int BF16OUT, int BN>
__global__ __launch_bounds__(256) void gemm_bt(const unsigned short* __restrict__ A,
                                               const unsigned short* __restrict__ Wall,
                                               const float* __restrict__ b0,
                                               const float* __restrict__ b1,
                                               const float* __restrict__ b2,
                                               unsigned short* __restrict__ outb,
                                               float* __restrict__ outf) {
    constexpr int MI = (BN == 128) ? 4 : 2;
    constexpr int NI = 4;
    __shared__ __align__(16) unsigned short As[2][128 * 32];
    __shared__ __align__(16) unsigned short Bs[2][BN * 32];

    const int t = threadIdx.x;
    const int w = t >> 6, l = t & 63;
    const int bx = blockIdx.x;
    const int which = (BN == 128) ? (bx >> 3) : 0;
    const int n0 = (BN == 128) ? (bx & 7) * 128 : bx * 64;
    const int m0 = blockIdx.y * 128;
    const unsigned short* W = Wall + (size_t)which * (1024ull * 1024);
    const float* bias = (which == 0) ? b0 : (which == 1) ? b1 : b2;

    const int wr = (BN == 128) ? (w >> 1) * 64 : w * 32;
    const int wc = (BN == 128) ? (w & 1) * 64 : 0;

    f32x4 acc[MI][NI];
#pragma unroll
    for (int i = 0; i < MI; ++i)
#pragma unroll
        for (int j = 0; j < NI; ++j) acc[i][j] = f32x4{0.f, 0.f, 0.f, 0.f};

    // staging: per wave, A rows w*32..+31 (2 chunks of 16 rows); B likewise
    const unsigned short* Ag = A + (size_t)(m0 + w * 32 + (l >> 2)) * 1024 + (l & 3) * 8;
    const unsigned short* Wg =
        W + (size_t)(n0 + ((BN == 128) ? w * 32 : w * 16) + (l >> 2)) * 1024 + (l & 3) * 8;

    auto STAGE = [&](int buf, int k0) {
        gload16(Ag + k0, &As[buf][w * 1024]);
        gload16(Ag + k0 + 16 * 1024, &As[buf][w * 1024 + 512]);
        gload16(Wg + k0, &Bs[buf][(BN == 128) ? w * 1024 : w * 512]);
        if (BN == 128) gload16(Wg + k0 + 16 * 1024, &Bs[buf][w * 1024 + 512]);
    };

    STAGE(0, 0);
    __syncthreads();   // vmcnt(0) drain: buf0 ready

    for (int kt = 0; kt < 32; ++kt) {
        const int cur = kt & 1;
        if (kt + 1 < 32) STAGE(cur ^ 1, (kt + 1) * 32);   // in flight during MFMA

        short8 af[MI], bfr[NI];
#pragma unroll
        for (int mi = 0; mi < MI; ++mi)
            af[mi] = *(const short8*)&As[cur][(wr + mi * 16 + (l & 15)) * 32 + (l >> 4) * 8];
#pragma unroll
        for (int ni = 0; ni < NI; ++ni)
            bfr[ni] = *(const short8*)&Bs[cur][(wc + ni * 16 + (l & 15)) * 32 + (l >> 4) * 8];
#pragma unroll
        for (int mi = 0; mi < MI; ++mi)
#pragma unroll
            for (int ni = 0; ni < NI; ++ni)
                acc[mi][ni] = __builtin_amdgcn_mfma_f32_16x16x32_bf16(af[mi], bfr[ni],
                                                                      acc[mi][ni], 0, 0, 0);

        __syncthreads();   // drains vmcnt(0): next buffer ready; reads of cur done
    }

    const int g = l >> 4, c = l & 15;
#pragma unroll
    for (int ni = 0; ni < NI; ++ni) {
        const int n = n0 + wc + ni * 16 + c;
        const float bv = bias[n];
#pragma unroll
        for (int mi = 0; mi < MI; ++mi) {
#pragma unroll
            for (int j = 0; j < 4; ++j) {
                const size_t m = (size_t)(m0 + wr + mi * 16 + g * 4 + j);
                const float v = acc[mi][ni][j] + bv;
                if (BF16OUT)
                    (outb + (size_t)which * (4096ull * 1024))[m * 1024 + n] = f2bf(v);
                else
                    outf[m * 1024 + n] = v;
            }
        }
    }
}

// ---------------------------------------------------------------------------
// V transpose: per (b,h) [2048][64] -> [64][2048] (bf16), 64x64 LDS tiles.
// ---------------------------------------------------------------------------
__global__ __launch_bounds__(256) void transpose_v(const unsigned short* __restrict__ v,
                                                   unsigned short* __restrict__ vt) {
    __shared__ __align__(16) unsigned short L[64][72];
    const int t = threadIdx.x;
    const int st = blockIdx.x;   // s tile 0..31
    const int ht = blockIdx.y;   // head 0..15
    const int b = blockIdx.z;
    {
        const int r = t >> 2, cs = t & 3;
        const unsigned short* src =
            v + (size_t)(b * 16 + ht) * (SEQ * 64) + (size_t)(st * 64 + r) * 64 + cs * 16;
        *(uint4*)&L[r][cs * 16] = *(const uint4*)src;
        *(uint4*)&L[r][cs * 16 + 8] = *(const uint4*)(src + 8);
    }
    __syncthreads();
    {
        const int dr = t >> 2, ss = t & 3;
        unsigned short tmp[16];
#pragma unroll
        for (int e = 0; e < 16; ++e) tmp[e] = L[ss * 16 + e][dr];
        unsigned short* dst =
            vt + (size_t)(b * 16 + ht) * (SEQ * 64) + (size_t)dr * SEQ + st * 64 + ss * 16;
        *(uint4*)dst = *(uint4*)&tmp[0];
        *(uint4*)(dst + 8) = *(uint4*)&tmp[8];
    }
}

// ---------------------------------------------------------------------------
// BigBird MFMA attention (bf16 in, bf16 out), swapped-QK^T flash style.
// grid (32 qblk, 16 h, 2 b), 256 thr = 4 waves; wave w owns 16 q-rows.
// S^T = K·Q^T -> softmax in-lane + 2 shfl_xor;  O^T = V^T·P^T.
// ---------------------------------------------------------------------------
__global__ __launch_bounds__(256) void attn_mfma(const unsigned short* __restrict__ qb_,
                                                 const unsigned short* __restrict__ kb_,
                                                 const unsigned short* __restrict__ vtb_,
                                                 const int* __restrict__ srcb,
                                                 const int* __restrict__ tgtb,
                                                 unsigned short* __restrict__ outb) {
    __shared__ __align__(16) unsigned short Ks[64 * 72];
    __shared__ __align__(16) unsigned short Vs[64 * 72];   // V^T tile [d][key]
    __shared__ __align__(16) unsigned short Ps[4][16 * 72];

    const int t = threadIdx.x, w = t >> 6, l = t & 63;
    const int qi = blockIdx.x, h = blockIdx.y, b = blockIdx.z;
    const int g = l >> 4, c = l & 15;

    unsigned mask = 1u | (1u << (NB - 1)) | (1u << qi);
    if (qi > 0) mask |= 1u << (qi - 1);
    if (qi < NB - 1) mask |= 1u << (qi + 1);
#pragma unroll
    for (int tt = 0; tt < 3; ++tt)
        if (srcb[tt] == qi) mask |= 1u << (tgtb[tt] & 31);

    const size_t ho = (size_t)(b * 16 + h) * (SEQ * 64);
    const unsigned short* Q = qb_ + ho;
    const unsigned short* K = kb_ + ho;
    const unsigned short* VT = vtb_ + ho;

    short8 qf[2];
    {
        const unsigned short* qrow = Q + (size_t)(qi * 64 + w * 16 + c) * 64;
        qf[0] = *(const short8*)(qrow + g * 8);
        qf[1] = *(const short8*)(qrow + 32 + g * 8);
    }

    f32x4 oacc[4];
#pragma unroll
    for (int d = 0; d < 4; ++d) oacc[d] = f32x4{0.f, 0.f, 0.f, 0.f};
    float mrun = -INFINITY, lsum = 0.f;

    const int sr = t >> 2, sc = (t & 3) * 16;

    for (int kb = 0; kb < NB; ++kb) {
        if (!((mask >> kb) & 1u)) continue;

        const unsigned short* ksrc = K + (size_t)(kb * 64 + sr) * 64 + sc;
        const unsigned short* vsrc = VT + (size_t)sr * SEQ + kb * 64 + sc;
        uint4 k0 = *(const uint4*)ksrc, k1 = *(const uint4*)(ksrc + 8);
        uint4 v0 = *(const uint4*)vsrc, v1 = *(const uint4*)(vsrc + 8);

        __syncthreads();
        *(uint4*)&Ks[sr * 72 + sc] = k0;
        *(uint4*)&Ks[sr * 72 + sc + 8] = k1;
        *(uint4*)&Vs[sr * 72 + sc] = v0;
        *(uint4*)&Vs[sr * 72 + sc + 8] = v1;
        __syncthreads();

        f32x4 sacc[4];
#pragma unroll
        for (int kt = 0; kt < 4; ++kt) sacc[kt] = f32x4{0.f, 0.f, 0.f, 0.f};
#pragma unroll
        for (int kt = 0; kt < 4; ++kt) {
#pragma unroll
            for (int ks = 0; ks < 2; ++ks) {
                const short8 ka = *(const short8*)&Ks[(kt * 16 + c) * 72 + ks * 32 + g * 8];
                sacc[kt] = __builtin_amdgcn_mfma_f32_16x16x32_bf16(ka, qf[ks], sacc[kt], 0, 0, 0);
            }
        }

        float sv[16];
        float tmax = -INFINITY;
#pragma unroll
        for (int kt = 0; kt < 4; ++kt)
#pragma unroll
            for (int j = 0; j < 4; ++j) {
                const float x = sacc[kt][j] * 0.125f;
                sv[kt * 4 + j] = x;
                tmax = fmaxf(tmax, x);
            }
        tmax = fmaxf(tmax, __shfl_xor(tmax, 16));
        tmax = fmaxf(tmax, __shfl_xor(tmax, 32));
        const float newm = fmaxf(mrun, tmax);
        const float corr = __expf(mrun - newm);
        float ps = 0.f;
#pragma unroll
        for (int e = 0; e < 16; ++e) {
            const float p = __expf(sv[e] - newm);
            sv[e] = p;
            ps += p;
        }
        ps += __shfl_xor(ps, 16);
        ps += __shfl_xor(ps, 32);
        lsum = lsum * corr + ps;
        mrun = newm;
#pragma unroll
        for (int d = 0; d < 4; ++d)
#pragma unroll
            for (int j = 0; j < 4; ++j) oacc[d][j] *= corr;

        unsigned short* pw = &Ps[w][c * 72];
#pragma unroll
        for (int kt = 0; kt < 4; ++kt) {
            uint2 pk;
            pk.x = f2bf(sv[kt * 4 + 0]) | ((unsigned)f2bf(sv[kt * 4 + 1]) << 16);
            pk.y = f2bf(sv[kt * 4 + 2]) | ((unsigned)f2bf(sv[kt * 4 + 3]) << 16);
            *(uint2*)&pw[kt * 16 + g * 4] = pk;
        }
        asm volatile("s_waitcnt lgkmcnt(0)" ::: "memory");   // same-wave LDS RAW
        __builtin_amdgcn_sched_barrier(0);

#pragma unroll
        for (int ks = 0; ks < 2; ++ks) {
            const short8 pb = *(const short8*)&Ps[w][c * 72 + ks * 32 + g * 8];
#pragma unroll
            for (int dt = 0; dt < 4; ++dt) {
                const short8 va = *(const short8*)&Vs[(dt * 16 + c) * 72 + ks * 32 + g * 8];
                oacc[dt] = __builtin_amdgcn_mfma_f32_16x16x32_bf16(va, pb, oacc[dt], 0, 0, 0);
            }
        }
    }

    const float inv = 1.f / lsum;
    unsigned short* orow = outb + (size_t)(b * SEQ + qi * 64 + w * 16 + c) * 1024 + h * 64;
#pragma unroll
    for (int dt = 0; dt < 4; ++dt)
#pragma unroll
        for (int j = 0; j < 4; ++j)
            orow[dt * 16 + g * 4 + j] = f2bf(oacc[dt][j] * inv);
}

// ---------------------------------------------------------------------------
extern "C" void kernel_launch(void* const* d_in, const int* in_sizes, int n_in,
                              void* d_out, int out_size, void* d_ws, size_t ws_size,
                              hipStream_t stream) {
    const float* x  = (const float*)d_in[0];
    const float* Wq = (const float*)d_in[1];
    const float* bq = (const float*)d_in[2];
    const float* Wk = (const float*)d_in[3];
    const float* bk = (const float*)d_in[4];
    const float* Wv = (const float*)d_in[5];
    const float* bv = (const float*)d_in[6];
    const float* Wo = (const float*)d_in[7];
    const float* bo = (const float*)d_in[8];
    const int* srcb = (const int*)d_in[9];
    const int* tgtb = (const int*)d_in[10];

    unsigned short* wsu = (unsigned short*)d_ws;
    unsigned short* xbf   = wsu;                      // [0,        4194304)
    unsigned short* wqkv  = wsu + 4194304ull;         // [4194304,  7340032)
    unsigned short* wobf  = wsu + 7340032ull;         // [7340032,  8388608)
    unsigned short* qkvbf = wsu + 8388608ull;         // [8388608,  20971520) Q,K,V panes
    unsigned short* vtbf  = wsu + 20971520ull;        // [20971520, 25165824) V^T 2*16*64*2048
    unsigned short* attbf = wsu + 25165824ull;        // [25165824, 29360128)

    hipLaunchKernelGGL(cvt_bf16, dim3(1024), dim3(256), 0, stream, x, xbf, 524288);
    hipLaunchKernelGGL(cvt_w4, dim3(512, 4), dim3(256), 0, stream,
                       Wq, Wk, Wv, Wo,
                       wqkv, wqkv + 1048576ull, wqkv + 2097152ull, wobf);

    // fused QKV GEMM (which = blockIdx.x>>3), plain [m][n] outputs
    hipLaunchKernelGGL((gemm_bt<1, 128>), dim3(24, 32), dim3(256), 0, stream,
                       xbf, wqkv, bq, bk, bv, qkvbf, (float*)nullptr);

    hipLaunchKernelGGL(transpose_v, dim3(32, 16, 2), dim3(256), 0, stream,
                       qkvbf + 2ull * 4194304ull, vtbf);

    hipLaunchKernelGGL(attn_mfma, dim3(32, 16, 2), dim3(256), 0, stream,
                       qkvbf, qkvbf + 4194304ull, vtbf, srcb, tgtb, attbf);

    // O projection -> fp32 d_out; BN=64 -> 512 wgs (2/CU)
    hipLaunchKernelGGL((gemm_bt<0, 64>), dim3(16, 32), dim3(256), 0, stream,
                       attbf, wobf, bo, bo, bo, (unsigned short*)nullptr, (float*)d_out);

    (void)in_sizes; (void)n_in; (void)out_size; (void)ws_size;
}

// Round 8
// 97.060 us; speedup vs baseline: 1.0706x; 1.0706x over previous
//
#include <hip/hip_runtime.h>
#include <math.h>

typedef __attribute__((ext_vector_type(8))) short short8;
typedef __attribute__((ext_vector_type(4))) float f32x4;

#define SEQ 2048
#define NB  32

__device__ __forceinline__ unsigned short f2bf(float f) {
    unsigned u = __float_as_uint(f);
    u = (u + 0x7FFFu + ((u >> 16) & 1u)) >> 16;   // RNE
    return (unsigned short)u;
}

// async global->LDS, 16B per lane; LDS dest = wave-uniform base + lane*16
__device__ __forceinline__ void gload16(const unsigned short* g, unsigned short* l) {
    __builtin_amdgcn_global_load_lds(
        (__attribute__((address_space(1))) void*)(void*)(g),
        (__attribute__((address_space(3))) void*)(l), 16, 0, 0);
}

// ---------------------------------------------------------------------------
// fp32 -> bf16 (RNE), 8 elems/thread, grid-stride
// ---------------------------------------------------------------------------
__global__ __launch_bounds__(256) void cvt_bf16(const float* __restrict__ in,
                                                unsigned short* __restrict__ out, int n8) {
    int i = blockIdx.x * 256 + threadIdx.x;
    const int stride = gridDim.x * 256;
    for (; i < n8; i += stride) {
        const float4 a = ((const float4*)in)[i * 2];
        const float4 b = ((const float4*)in)[i * 2 + 1];
        uint4 o;
        o.x = f2bf(a.x) | ((unsigned)f2bf(a.y) << 16);
        o.y = f2bf(a.z) | ((unsigned)f2bf(a.w) << 16);
        o.z = f2bf(b.x) | ((unsigned)f2bf(b.y) << 16);
        o.w = f2bf(b.z) | ((unsigned)f2bf(b.w) << 16);
        ((uint4*)out)[i] = o;
    }
}

// 4 weight matrices in one dispatch (blockIdx.y selects)
__global__ __launch_bounds__(256) void cvt_w4(const float* __restrict__ w0,
                                              const float* __restrict__ w1,
                                              const float* __restrict__ w2,
                                              const float* __restrict__ w3,
                                              unsigned short* __restrict__ o0,
                                              unsigned short* __restrict__ o1,
                                              unsigned short* __restrict__ o2,
                                              unsigned short* __restrict__ o3) {
    const int which = blockIdx.y;
    const float* in = (which == 0) ? w0 : (which == 1) ? w1 : (which == 2) ? w2 : w3;
    unsigned short* out = (which == 0) ? o0 : (which == 1) ? o1 : (which == 2) ? o2 : o3;
    int i = blockIdx.x * 256 + threadIdx.x;
    const int stride = gridDim.x * 256;
    for (; i < 131072; i += stride) {
        const float4 a = ((const float4*)in)[i * 2];
        const float4 b = ((const float4*)in)[i * 2 + 1];
        uint4 o;
        o.x = f2bf(a.x) | ((unsigned)f2bf(a.y) << 16);
        o.y = f2bf(a.z) | ((unsigned)f2bf(a.w) << 16);
        o.z = f2bf(b.x) | ((unsigned)f2bf(b.y) << 16);
        o.w = f2bf(b.z) | ((unsigned)f2bf(b.w) << 16);
        ((uint4*)out)[i] = o;
    }
}

// ---------------------------------------------------------------------------
// bf16 MFMA GEMM: C[M,1024] = A[M,1024] @ W[1024,1024]^T + bias, M=4096.
// BM=128, BK=32, 256 thr. gload_lds dbuf with COUNTED vmcnt (T4):
//   half-step: STAGE(other) ; vmcnt(NLOAD) [cur ready, prefetch in flight]
//              ; s_barrier ; ds_read+MFMA(cur) ; lgkmcnt(0) ; s_barrier
// K-loop unrolled x2 so buffer indices are compile-time (round-7 lesson:
// runtime cur cost 22% VALUBusy; __syncthreads drains vmcnt(0) = no pipeline).
// BN=128: 4 waves 2x2 (64x64 each), grid.x = 8*nW, which=bx>>3 (QKV fused).
// BN=64:  4 waves 4x1 (32x64 each), grid.x = 16, which=0 (O projection).
// NOTE (round-3 lesson): head split is a .view — head h = GEMM ROWS
// h*128..h*128+127 per batch, NOT column slices.
// ---------------------------------------------------------------------------
template <int BF16OUT, int BN>
__global__ __launch_bounds__(256) void gemm_bt(const unsigned short* __restrict__ A,
                                               const unsigned short* __restrict__ Wall,
                                               const float* __restrict__ b0,
                                               const float* __restrict__ b1,
                                               const float* __restrict__ b2,
                                               unsigned short* __restrict__ outb,
                                               float* __restrict__ outf) {
    constexpr int MI = (BN == 128) ? 4 : 2;
    constexpr int NI = 4;
    __shared__ __align__(16) unsigned short As[2][128 * 32];
    __shared__ __align__(16) unsigned short Bs[2][BN * 32];

    const int t = threadIdx.x;
    const int w = t >> 6, l = t & 63;
    const int bx = blockIdx.x;
    const int which = (BN == 128) ? (bx >> 3) : 0;
    const int n0 = (BN == 128) ? (bx & 7) * 128 : bx * 64;
    const int m0 = blockIdx.y * 128;
    const unsigned short* W = Wall + (size_t)which * (1024ull * 1024);
    const float* bias = (which == 0) ? b0 : (which == 1) ? b1 : b2;

    const int wr = (BN == 128) ? (w >> 1) * 64 : w * 32;
    const int wc = (BN == 128) ? (w & 1) * 64 : 0;

    f32x4 acc[MI][NI];
#pragma unroll
    for (int i = 0; i < MI; ++i)
#pragma unroll
        for (int j = 0; j < NI; ++j) acc[i][j] = f32x4{0.f, 0.f, 0.f, 0.f};

    // staging: per wave, A rows w*32..+31 (2 chunks of 16 rows); B likewise
    const unsigned short* Ag = A + (size_t)(m0 + w * 32 + (l >> 2)) * 1024 + (l & 3) * 8;
    const unsigned short* Wg =
        W + (size_t)(n0 + ((BN == 128) ? w * 32 : w * 16) + (l >> 2)) * 1024 + (l & 3) * 8;

    auto STAGE = [&](unsigned short* Asb, unsigned short* Bsb, int k0) {
        gload16(Ag + k0, Asb + w * 1024);
        gload16(Ag + k0 + 16 * 1024, Asb + w * 1024 + 512);
        gload16(Wg + k0, Bsb + ((BN == 128) ? w * 1024 : w * 512));
        if (BN == 128) gload16(Wg + k0 + 16 * 1024, Bsb + w * 1024 + 512);
    };
    auto COMPUTE = [&](const unsigned short* Asb, const unsigned short* Bsb) {
        short8 af[MI], bfr[NI];
#pragma unroll
        for (int mi = 0; mi < MI; ++mi)
            af[mi] = *(const short8*)&Asb[(wr + mi * 16 + (l & 15)) * 32 + (l >> 4) * 8];
#pragma unroll
        for (int ni = 0; ni < NI; ++ni)
            bfr[ni] = *(const short8*)&Bsb[(wc + ni * 16 + (l & 15)) * 32 + (l >> 4) * 8];
#pragma unroll
        for (int mi = 0; mi < MI; ++mi)
#pragma unroll
            for (int ni = 0; ni < NI; ++ni)
                acc[mi][ni] = __builtin_amdgcn_mfma_f32_16x16x32_bf16(af[mi], bfr[ni],
                                                                      acc[mi][ni], 0, 0, 0);
    };
#define WAITV_INFLIGHT()                                                  \
    do {                                                                  \
        if constexpr (BN == 128)                                          \
            asm volatile("s_waitcnt vmcnt(4)" ::: "memory");              \
        else                                                              \
            asm volatile("s_waitcnt vmcnt(3)" ::: "memory");              \
        __builtin_amdgcn_sched_barrier(0);                                \
    } while (0)
#define BAR()                                                             \
    do {                                                                  \
        __builtin_amdgcn_s_barrier();                                     \
        __builtin_amdgcn_sched_barrier(0);                                \
    } while (0)
#define READS_DONE_BAR()                                                  \
    do {                                                                  \
        asm volatile("s_waitcnt lgkmcnt(0)" ::: "memory");                \
        __builtin_amdgcn_sched_barrier(0);                                \
        __builtin_amdgcn_s_barrier();                                     \
        __builtin_amdgcn_sched_barrier(0);                                \
    } while (0)

    STAGE(As[0], Bs[0], 0);
#pragma unroll 1
    for (int kt2 = 0; kt2 < 16; ++kt2) {
        // ---- half A: compute buf0, prefetch buf1 ----
        STAGE(As[1], Bs[1], (kt2 * 2 + 1) * 32);
        WAITV_INFLIGHT();      // buf0 loads done; buf1's stay in flight
        BAR();
        COMPUTE(As[0], Bs[0]);
        READS_DONE_BAR();      // all waves done reading buf0 (lgkm only)

        // ---- half B: compute buf1, prefetch buf0 ----
        if (kt2 < 15) {
            STAGE(As[0], Bs[0], (kt2 * 2 + 2) * 32);
            WAITV_INFLIGHT();
        } else {
            asm volatile("s_waitcnt vmcnt(0)" ::: "memory");
            __builtin_amdgcn_sched_barrier(0);
        }
        BAR();
        COMPUTE(As[1], Bs[1]);
        if (kt2 < 15) READS_DONE_BAR();
    }
#undef WAITV_INFLIGHT
#undef BAR
#undef READS_DONE_BAR

    const int g = l >> 4, c = l & 15;
#pragma unroll
    for (int ni = 0; ni < NI; ++ni) {
        const int n = n0 + wc + ni * 16 + c;
        const float bv = bias[n];
#pragma unroll
        for (int mi = 0; mi < MI; ++mi) {
#pragma unroll
            for (int j = 0; j < 4; ++j) {
                const size_t m = (size_t)(m0 + wr + mi * 16 + g * 4 + j);
                const float v = acc[mi][ni][j] + bv;
                if (BF16OUT)
                    (outb + (size_t)which * (4096ull * 1024))[m * 1024 + n] = f2bf(v);
                else
                    outf[m * 1024 + n] = v;
            }
        }
    }
}

// ---------------------------------------------------------------------------
// V transpose: per (b,h) [2048][64] -> [64][2048] (bf16), 64x64 LDS tiles.
// ---------------------------------------------------------------------------
__global__ __launch_bounds__(256) void transpose_v(const unsigned short* __restrict__ v,
                                                   unsigned short* __restrict__ vt) {
    __shared__ __align__(16) unsigned short L[64][72];
    const int t = threadIdx.x;
    const int st = blockIdx.x;   // s tile 0..31
    const int ht = blockIdx.y;   // head 0..15
    const int b = blockIdx.z;
    {
        const int r = t >> 2, cs = t & 3;
        const unsigned short* src =
            v + (size_t)(b * 16 + ht) * (SEQ * 64) + (size_t)(st * 64 + r) * 64 + cs * 16;
        *(uint4*)&L[r][cs * 16] = *(const uint4*)src;
        *(uint4*)&L[r][cs * 16 + 8] = *(const uint4*)(src + 8);
    }
    __syncthreads();
    {
        const int dr = t >> 2, ss = t & 3;
        unsigned short tmp[16];
#pragma unroll
        for (int e = 0; e < 16; ++e) tmp[e] = L[ss * 16 + e][dr];
        unsigned short* dst =
            vt + (size_t)(b * 16 + ht) * (SEQ * 64) + (size_t)dr * SEQ + st * 64 + ss * 16;
        *(uint4*)dst = *(uint4*)&tmp[0];
        *(uint4*)(dst + 8) = *(uint4*)&tmp[8];
    }
}

// ---------------------------------------------------------------------------
// BigBird MFMA attention (bf16 in, bf16 out), swapped-QK^T flash style.
// grid (32 qblk, 16 h, 2 b), 256 thr = 4 waves; wave w owns 16 q-rows.
// S^T = K·Q^T -> softmax in-lane + 2 shfl_xor;  O^T = V^T·P^T.
// ---------------------------------------------------------------------------
__global__ __launch_bounds__(256) void attn_mfma(const unsigned short* __restrict__ qb_,
                                                 const unsigned short* __restrict__ kb_,
                                                 const unsigned short* __restrict__ vtb_,
                                                 const int* __restrict__ srcb,
                                                 const int* __restrict__ tgtb,
                                                 unsigned short* __restrict__ outb) {
    __shared__ __align__(16) unsigned short Ks[64 * 72];
    __shared__ __align__(16) unsigned short Vs[64 * 72];   // V^T tile [d][key]
    __shared__ __align__(16) unsigned short Ps[4][16 * 72];

    const int t = threadIdx.x, w = t >> 6, l = t & 63;
    const int qi = blockIdx.x, h = blockIdx.y, b = blockIdx.z;
    const int g = l >> 4, c = l & 15;

    unsigned mask = 1u | (1u << (NB - 1)) | (1u << qi);
    if (qi > 0) mask |= 1u << (qi - 1);
    if (qi < NB - 1) mask |= 1u << (qi + 1);
#pragma unroll
    for (int tt = 0; tt < 3; ++tt)
        if (srcb[tt] == qi) mask |= 1u << (tgtb[tt] & 31);

    const size_t ho = (size_t)(b * 16 + h) * (SEQ * 64);
    const unsigned short* Q = qb_ + ho;
    const unsigned short* K = kb_ + ho;
    const unsigned short* VT = vtb_ + ho;

    short8 qf[2];
    {
        const unsigned short* qrow = Q + (size_t)(qi * 64 + w * 16 + c) * 64;
        qf[0] = *(const short8*)(qrow + g * 8);
        qf[1] = *(const short8*)(qrow + 32 + g * 8);
    }

    f32x4 oacc[4];
#pragma unroll
    for (int d = 0; d < 4; ++d) oacc[d] = f32x4{0.f, 0.f, 0.f, 0.f};
    float mrun = -INFINITY, lsum = 0.f;

    const int sr = t >> 2, sc = (t & 3) * 16;

    for (int kb = 0; kb < NB; ++kb) {
        if (!((mask >> kb) & 1u)) continue;

        const unsigned short* ksrc = K + (size_t)(kb * 64 + sr) * 64 + sc;
        const unsigned short* vsrc = VT + (size_t)sr * SEQ + kb * 64 + sc;
        uint4 k0 = *(const uint4*)ksrc, k1 = *(const uint4*)(ksrc + 8);
        uint4 v0 = *(const uint4*)vsrc, v1 = *(const uint4*)(vsrc + 8);

        __syncthreads();
        *(uint4*)&Ks[sr * 72 + sc] = k0;
        *(uint4*)&Ks[sr * 72 + sc + 8] = k1;
        *(uint4*)&Vs[sr * 72 + sc] = v0;
        *(uint4*)&Vs[sr * 72 + sc + 8] = v1;
        __syncthreads();

        f32x4 sacc[4];
#pragma unroll
        for (int kt = 0; kt < 4; ++kt) sacc[kt] = f32x4{0.f, 0.f, 0.f, 0.f};
#pragma unroll
        for (int kt = 0; kt < 4; ++kt) {
#pragma unroll
            for (int ks = 0; ks < 2; ++ks) {
                const short8 ka = *(const short8*)&Ks[(kt * 16 + c) * 72 + ks * 32 + g * 8];
                sacc[kt] = __builtin_amdgcn_mfma_f32_16x16x32_bf16(ka, qf[ks], sacc[kt], 0, 0, 0);
            }
        }

        float sv[16];
        float tmax = -INFINITY;
#pragma unroll
        for (int kt = 0; kt < 4; ++kt)
#pragma unroll
            for (int j = 0; j < 4; ++j) {
                const float x = sacc[kt][j] * 0.125f;
                sv[kt * 4 + j] = x;
                tmax = fmaxf(tmax, x);
            }
        tmax = fmaxf(tmax, __shfl_xor(tmax, 16));
        tmax = fmaxf(tmax, __shfl_xor(tmax, 32));
        const float newm = fmaxf(mrun, tmax);
        const float corr = __expf(mrun - newm);
        float ps = 0.f;
#pragma unroll
        for (int e = 0; e < 16; ++e) {
            const float p = __expf(sv[e] - newm);
            sv[e] = p;
            ps += p;
        }
        ps += __shfl_xor(ps, 16);
        ps += __shfl_xor(ps, 32);
        lsum = lsum * corr + ps;
        mrun = newm;
#pragma unroll
        for (int d = 0; d < 4; ++d)
#pragma unroll
            for (int j = 0; j < 4; ++j) oacc[d][j] *= corr;

        unsigned short* pw = &Ps[w][c * 72];
#pragma unroll
        for (int kt = 0; kt < 4; ++kt) {
            uint2 pk;
            pk.x = f2bf(sv[kt * 4 + 0]) | ((unsigned)f2bf(sv[kt * 4 + 1]) << 16);
            pk.y = f2bf(sv[kt * 4 + 2]) | ((unsigned)f2bf(sv[kt * 4 + 3]) << 16);
            *(uint2*)&pw[kt * 16 + g * 4] = pk;
        }
        asm volatile("s_waitcnt lgkmcnt(0)" ::: "memory");   // same-wave LDS RAW
        __builtin_amdgcn_sched_barrier(0);

#pragma unroll
        for (int ks = 0; ks < 2; ++ks) {
            const short8 pb = *(const short8*)&Ps[w][c * 72 + ks * 32 + g * 8];
#pragma unroll
            for (int dt = 0; dt < 4; ++dt) {
                const short8 va = *(const short8*)&Vs[(dt * 16 + c) * 72 + ks * 32 + g * 8];
                oacc[dt] = __builtin_amdgcn_mfma_f32_16x16x32_bf16(va, pb, oacc[dt], 0, 0, 0);
            }
        }
    }

    const float inv = 1.f / lsum;
    unsigned short* orow = outb + (size_t)(b * SEQ + qi * 64 + w * 16 + c) * 1024 + h * 64;
#pragma unroll
    for (int dt = 0; dt < 4; ++dt)
#pragma unroll
        for (int j = 0; j < 4; ++j)
            orow[dt * 16 + g * 4 + j] = f2bf(oacc[dt][j] * inv);
}

// ---------------------------------------------------------------------------
extern "C" void kernel_launch(void* const* d_in, const int* in_sizes, int n_in,
                              void* d_out, int out_size, void* d_ws, size_t ws_size,
                              hipStream_t stream) {
    const float* x  = (const float*)d_in[0];
    const float* Wq = (const float*)d_in[1];
    const float* bq = (const float*)d_in[2];
    const float* Wk = (const float*)d_in[3];
    const float* bk = (const float*)d_in[4];
    const float* Wv = (const float*)d_in[5];
    const float* bv = (const float*)d_in[6];
    const float* Wo = (const float*)d_in[7];
    const float* bo = (const float*)d_in[8];
    const int* srcb = (const int*)d_in[9];
    const int* tgtb = (const int*)d_in[10];

    unsigned short* wsu = (unsigned short*)d_ws;
    unsigned short* xbf   = wsu;                      // [0,        4194304)
    unsigned short* wqkv  = wsu + 4194304ull;         // [4194304,  7340032)
    unsigned short* wobf  = wsu + 7340032ull;         // [7340032,  8388608)
    unsigned short* qkvbf = wsu + 8388608ull;         // [8388608,  20971520) Q,K,V panes
    unsigned short* vtbf  = wsu + 20971520ull;        // [20971520, 25165824) V^T 2*16*64*2048
    unsigned short* attbf = wsu + 25165824ull;        // [25165824, 29360128)

    hipLaunchKernelGGL(cvt_bf16, dim3(1024), dim3(256), 0, stream, x, xbf, 524288);
    hipLaunchKernelGGL(cvt_w4, dim3(512, 4), dim3(256), 0, stream,
                       Wq, Wk, Wv, Wo,
                       wqkv, wqkv + 1048576ull, wqkv + 2097152ull, wobf);

    // fused QKV GEMM (which = blockIdx.x>>3), plain [m][n] outputs
    hipLaunchKernelGGL((gemm_bt<1, 128>), dim3(24, 32), dim3(256), 0, stream,
                       xbf, wqkv, bq, bk, bv, qkvbf, (float*)nullptr);

    hipLaunchKernelGGL(transpose_v, dim3(32, 16, 2), dim3(256), 0, stream,
                       qkvbf + 2ull * 4194304ull, vtbf);

    hipLaunchKernelGGL(attn_mfma, dim3(32, 16, 2), dim3(256), 0, stream,
                       qkvbf, qkvbf + 4194304ull, vtbf, srcb, tgtb, attbf);

    // O projection -> fp32 d_out; BN=64 -> 512 wgs (2/CU)
    hipLaunchKernelGGL((gemm_bt<0, 64>), dim3(16, 32), dim3(256), 0, stream,
                       attbf, wobf, bo, bo, bo, (unsigned short*)nullptr, (float*)d_out);

    (void)in_sizes; (void)n_in; (void)out_size; (void)ws_size;
}

// Round 9
// 92.823 us; speedup vs baseline: 1.1195x; 1.0457x over previous
//
#include <hip/hip_runtime.h>
#include <math.h>

typedef __attribute__((ext_vector_type(8))) short short8;
typedef __attribute__((ext_vector_type(4))) float f32x4;

#define SEQ 2048
#define NB  32

__device__ __forceinline__ unsigned short f2bf(float f) {
    unsigned u = __float_as_uint(f);
    u = (u + 0x7FFFu + ((u >> 16) & 1u)) >> 16;   // RNE
    return (unsigned short)u;
}

// async global->LDS, 16B per lane; LDS dest = wave-uniform base + lane*16
__device__ __forceinline__ void gload16(const unsigned short* g, unsigned short* l) {
    __builtin_amdgcn_global_load_lds(
        (__attribute__((address_space(1))) void*)(void*)(g),
        (__attribute__((address_space(3))) void*)(l), 16, 0, 0);
}

// ---------------------------------------------------------------------------
// fp32 -> bf16 (RNE): 5 tensors in ONE dispatch. blockIdx.y selects the job:
// y=0: x (4096x1024), y=1..4: Wq/Wk/Wv/Wo (1024x1024 each).
// ---------------------------------------------------------------------------
__global__ __launch_bounds__(256) void cvt_all(const float* __restrict__ x,
                                               const float* __restrict__ w0,
                                               const float* __restrict__ w1,
                                               const float* __restrict__ w2,
                                               const float* __restrict__ w3,
                                               unsigned short* __restrict__ ox,
                                               unsigned short* __restrict__ o0,
                                               unsigned short* __restrict__ o1,
                                               unsigned short* __restrict__ o2,
                                               unsigned short* __restrict__ o3) {
    const int which = blockIdx.y;
    const float* in = (which == 0) ? x : (which == 1) ? w0 : (which == 2) ? w1
                       : (which == 3) ? w2 : w3;
    unsigned short* out = (which == 0) ? ox : (which == 1) ? o0 : (which == 2) ? o1
                          : (which == 3) ? o2 : o3;
    const int n8 = (which == 0) ? 524288 : 131072;
    int i = blockIdx.x * 256 + threadIdx.x;
    const int stride = gridDim.x * 256;
    for (; i < n8; i += stride) {
        const float4 a = ((const float4*)in)[i * 2];
        const float4 b = ((const float4*)in)[i * 2 + 1];
        uint4 o;
        o.x = f2bf(a.x) | ((unsigned)f2bf(a.y) << 16);
        o.y = f2bf(a.z) | ((unsigned)f2bf(a.w) << 16);
        o.z = f2bf(b.x) | ((unsigned)f2bf(b.y) << 16);
        o.w = f2bf(b.z) | ((unsigned)f2bf(b.w) << 16);
        ((uint4*)out)[i] = o;
    }
}

// ---------------------------------------------------------------------------
// bf16 MFMA GEMM (frozen at round-8 structure: gload_lds dbuf, counted vmcnt,
// K-loop unrolled x2 for compile-time buffer indices).
// BN=128: 4 waves 2x2 (64x64 each), grid.x = 8*nW, which=bx>>3 (QKV fused).
// BN=64:  4 waves 4x1 (32x64 each), grid.x = 16, which=0 (O projection).
// NOTE (round-3 lesson): head split is a .view — head h = GEMM ROWS
// h*128..h*128+127 per batch, NOT column slices.
// ---------------------------------------------------------------------------
template <int BF16OUT, int BN>
__global__ __launch_bounds__(256) void gemm_bt(const unsigned short* __restrict__ A,
                                               const unsigned short* __restrict__ Wall,
                                               const float* __restrict__ b0,
                                               const float* __restrict__ b1,
                                               const float* __restrict__ b2,
                                               unsigned short* __restrict__ outb,
                                               float* __restrict__ outf) {
    constexpr int MI = (BN == 128) ? 4 : 2;
    constexpr int NI = 4;
    __shared__ __align__(16) unsigned short As[2][128 * 32];
    __shared__ __align__(16) unsigned short Bs[2][BN * 32];

    const int t = threadIdx.x;
    const int w = t >> 6, l = t & 63;
    const int bx = blockIdx.x;
    const int which = (BN == 128) ? (bx >> 3) : 0;
    const int n0 = (BN == 128) ? (bx & 7) * 128 : bx * 64;
    const int m0 = blockIdx.y * 128;
    const unsigned short* W = Wall + (size_t)which * (1024ull * 1024);
    const float* bias = (which == 0) ? b0 : (which == 1) ? b1 : b2;

    const int wr = (BN == 128) ? (w >> 1) * 64 : w * 32;
    const int wc = (BN == 128) ? (w & 1) * 64 : 0;

    f32x4 acc[MI][NI];
#pragma unroll
    for (int i = 0; i < MI; ++i)
#pragma unroll
        for (int j = 0; j < NI; ++j) acc[i][j] = f32x4{0.f, 0.f, 0.f, 0.f};

    const unsigned short* Ag = A + (size_t)(m0 + w * 32 + (l >> 2)) * 1024 + (l & 3) * 8;
    const unsigned short* Wg =
        W + (size_t)(n0 + ((BN == 128) ? w * 32 : w * 16) + (l >> 2)) * 1024 + (l & 3) * 8;

    auto STAGE = [&](unsigned short* Asb, unsigned short* Bsb, int k0) {
        gload16(Ag + k0, Asb + w * 1024);
        gload16(Ag + k0 + 16 * 1024, Asb + w * 1024 + 512);
        gload16(Wg + k0, Bsb + ((BN == 128) ? w * 1024 : w * 512));
        if (BN == 128) gload16(Wg + k0 + 16 * 1024, Bsb + w * 1024 + 512);
    };
    auto COMPUTE = [&](const unsigned short* Asb, const unsigned short* Bsb) {
        short8 af[MI], bfr[NI];
#pragma unroll
        for (int mi = 0; mi < MI; ++mi)
            af[mi] = *(const short8*)&Asb[(wr + mi * 16 + (l & 15)) * 32 + (l >> 4) * 8];
#pragma unroll
        for (int ni = 0; ni < NI; ++ni)
            bfr[ni] = *(const short8*)&Bsb[(wc + ni * 16 + (l & 15)) * 32 + (l >> 4) * 8];
#pragma unroll
        for (int mi = 0; mi < MI; ++mi)
#pragma unroll
            for (int ni = 0; ni < NI; ++ni)
                acc[mi][ni] = __builtin_amdgcn_mfma_f32_16x16x32_bf16(af[mi], bfr[ni],
                                                                      acc[mi][ni], 0, 0, 0);
    };
#define WAITV_INFLIGHT()                                                  \
    do {                                                                  \
        if constexpr (BN == 128)                                          \
            asm volatile("s_waitcnt vmcnt(4)" ::: "memory");              \
        else                                                              \
            asm volatile("s_waitcnt vmcnt(3)" ::: "memory");              \
        __builtin_amdgcn_sched_barrier(0);                                \
    } while (0)
#define BAR()                                                             \
    do {                                                                  \
        __builtin_amdgcn_s_barrier();                                     \
        __builtin_amdgcn_sched_barrier(0);                                \
    } while (0)
#define READS_DONE_BAR()                                                  \
    do {                                                                  \
        asm volatile("s_waitcnt lgkmcnt(0)" ::: "memory");                \
        __builtin_amdgcn_sched_barrier(0);                                \
        __builtin_amdgcn_s_barrier();                                     \
        __builtin_amdgcn_sched_barrier(0);                                \
    } while (0)

    STAGE(As[0], Bs[0], 0);
#pragma unroll 1
    for (int kt2 = 0; kt2 < 16; ++kt2) {
        // ---- half A: compute buf0, prefetch buf1 ----
        STAGE(As[1], Bs[1], (kt2 * 2 + 1) * 32);
        WAITV_INFLIGHT();      // buf0 loads done; buf1's stay in flight
        BAR();
        COMPUTE(As[0], Bs[0]);
        READS_DONE_BAR();      // all waves done reading buf0 (lgkm only)

        // ---- half B: compute buf1, prefetch buf0 ----
        if (kt2 < 15) {
            STAGE(As[0], Bs[0], (kt2 * 2 + 2) * 32);
            WAITV_INFLIGHT();
        } else {
            asm volatile("s_waitcnt vmcnt(0)" ::: "memory");
            __builtin_amdgcn_sched_barrier(0);
        }
        BAR();
        COMPUTE(As[1], Bs[1]);
        if (kt2 < 15) READS_DONE_BAR();
    }
#undef WAITV_INFLIGHT
#undef BAR
#undef READS_DONE_BAR

    const int g = l >> 4, c = l & 15;
#pragma unroll
    for (int ni = 0; ni < NI; ++ni) {
        const int n = n0 + wc + ni * 16 + c;
        const float bv = bias[n];
#pragma unroll
        for (int mi = 0; mi < MI; ++mi) {
#pragma unroll
            for (int j = 0; j < 4; ++j) {
                const size_t m = (size_t)(m0 + wr + mi * 16 + g * 4 + j);
                const float v = acc[mi][ni][j] + bv;
                if (BF16OUT)
                    (outb + (size_t)which * (4096ull * 1024))[m * 1024 + n] = f2bf(v);
                else
                    outf[m * 1024 + n] = v;
            }
        }
    }
}

// ---------------------------------------------------------------------------
// BigBird MFMA attention (bf16 in, bf16 out), swapped-QK^T flash style.
// grid (32 qblk, 16 h, 2 b), 256 thr = 4 waves; wave w owns 16 q-rows.
// S^T = K·Q^T -> softmax in-lane + 2 shfl_xor;  O^T = V^T·P^T.
// V transpose now done IN the staging write (round-9): read V rows coalesced,
// scatter ds_write_b16 into Vs[d][key] — replaces the transpose_v kernel.
// ---------------------------------------------------------------------------
__global__ __launch_bounds__(256) void attn_mfma(const unsigned short* __restrict__ qb_,
                                                 const unsigned short* __restrict__ kb_,
                                                 const unsigned short* __restrict__ vb_,
                                                 const int* __restrict__ srcb,
                                                 const int* __restrict__ tgtb,
                                                 unsigned short* __restrict__ outb) {
    __shared__ __align__(16) unsigned short Ks[64 * 72];
    __shared__ __align__(16) unsigned short Vs[64 * 72];   // V^T tile [d][key]
    __shared__ __align__(16) unsigned short Ps[4][16 * 72];

    const int t = threadIdx.x, w = t >> 6, l = t & 63;
    const int qi = blockIdx.x, h = blockIdx.y, b = blockIdx.z;
    const int g = l >> 4, c = l & 15;

    unsigned mask = 1u | (1u << (NB - 1)) | (1u << qi);
    if (qi > 0) mask |= 1u << (qi - 1);
    if (qi < NB - 1) mask |= 1u << (qi + 1);
#pragma unroll
    for (int tt = 0; tt < 3; ++tt)
        if (srcb[tt] == qi) mask |= 1u << (tgtb[tt] & 31);

    const size_t ho = (size_t)(b * 16 + h) * (SEQ * 64);
    const unsigned short* Q = qb_ + ho;
    const unsigned short* K = kb_ + ho;
    const unsigned short* V = vb_ + ho;

    short8 qf[2];
    {
        const unsigned short* qrow = Q + (size_t)(qi * 64 + w * 16 + c) * 64;
        qf[0] = *(const short8*)(qrow + g * 8);
        qf[1] = *(const short8*)(qrow + 32 + g * 8);
    }

    f32x4 oacc[4];
#pragma unroll
    for (int d = 0; d < 4; ++d) oacc[d] = f32x4{0.f, 0.f, 0.f, 0.f};
    float mrun = -INFINITY, lsum = 0.f;

    const int sr = t >> 2, sc = (t & 3) * 16;

    for (int kb = 0; kb < NB; ++kb) {
        if (!((mask >> kb) & 1u)) continue;

        // K row (key sr, d sc..+15) and V row (key sr, d sc..+15), coalesced
        const unsigned short* ksrc = K + (size_t)(kb * 64 + sr) * 64 + sc;
        const unsigned short* vsrc = V + (size_t)(kb * 64 + sr) * 64 + sc;
        uint4 k0 = *(const uint4*)ksrc, k1 = *(const uint4*)(ksrc + 8);
        uint4 v0 = *(const uint4*)vsrc, v1 = *(const uint4*)(vsrc + 8);

        __syncthreads();
        *(uint4*)&Ks[sr * 72 + sc] = k0;
        *(uint4*)&Ks[sr * 72 + sc + 8] = k1;
        {   // transpose-on-write: Vs[d][key] = V[key][d]
            const unsigned short* p0 = (const unsigned short*)&v0;
            const unsigned short* p1 = (const unsigned short*)&v1;
#pragma unroll
            for (int e = 0; e < 8; ++e) {
                Vs[(sc + e) * 72 + sr] = p0[e];
                Vs[(sc + 8 + e) * 72 + sr] = p1[e];
            }
        }
        __syncthreads();

        f32x4 sacc[4];
#pragma unroll
        for (int kt = 0; kt < 4; ++kt) sacc[kt] = f32x4{0.f, 0.f, 0.f, 0.f};
#pragma unroll
        for (int kt = 0; kt < 4; ++kt) {
#pragma unroll
            for (int ks = 0; ks < 2; ++ks) {
                const short8 ka = *(const short8*)&Ks[(kt * 16 + c) * 72 + ks * 32 + g * 8];
                sacc[kt] = __builtin_amdgcn_mfma_f32_16x16x32_bf16(ka, qf[ks], sacc[kt], 0, 0, 0);
            }
        }

        float sv[16];
        float tmax = -INFINITY;
#pragma unroll
        for (int kt = 0; kt < 4; ++kt)
#pragma unroll
            for (int j = 0; j < 4; ++j) {
                const float x = sacc[kt][j] * 0.125f;
                sv[kt * 4 + j] = x;
                tmax = fmaxf(tmax, x);
            }
        tmax = fmaxf(tmax, __shfl_xor(tmax, 16));
        tmax = fmaxf(tmax, __shfl_xor(tmax, 32));
        const float newm = fmaxf(mrun, tmax);
        const float corr = __expf(mrun - newm);
        float ps = 0.f;
#pragma unroll
        for (int e = 0; e < 16; ++e) {
            const float p = __expf(sv[e] - newm);
            sv[e] = p;
            ps += p;
        }
        ps += __shfl_xor(ps, 16);
        ps += __shfl_xor(ps, 32);
        lsum = lsum * corr + ps;
        mrun = newm;
#pragma unroll
        for (int d = 0; d < 4; ++d)
#pragma unroll
            for (int j = 0; j < 4; ++j) oacc[d][j] *= corr;

        unsigned short* pw = &Ps[w][c * 72];
#pragma unroll
        for (int kt = 0; kt < 4; ++kt) {
            uint2 pk;
            pk.x = f2bf(sv[kt * 4 + 0]) | ((unsigned)f2bf(sv[kt * 4 + 1]) << 16);
            pk.y = f2bf(sv[kt * 4 + 2]) | ((unsigned)f2bf(sv[kt * 4 + 3]) << 16);
            *(uint2*)&pw[kt * 16 + g * 4] = pk;
        }
        asm volatile("s_waitcnt lgkmcnt(0)" ::: "memory");   // same-wave LDS RAW
        __builtin_amdgcn_sched_barrier(0);

#pragma unroll
        for (int ks = 0; ks < 2; ++ks) {
            const short8 pb = *(const short8*)&Ps[w][c * 72 + ks * 32 + g * 8];
#pragma unroll
            for (int dt = 0; dt < 4; ++dt) {
                const short8 va = *(const short8*)&Vs[(dt * 16 + c) * 72 + ks * 32 + g * 8];
                oacc[dt] = __builtin_amdgcn_mfma_f32_16x16x32_bf16(va, pb, oacc[dt], 0, 0, 0);
            }
        }
    }

    const float inv = 1.f / lsum;
    unsigned short* orow = outb + (size_t)(b * SEQ + qi * 64 + w * 16 + c) * 1024 + h * 64;
#pragma unroll
    for (int dt = 0; dt < 4; ++dt)
#pragma unroll
        for (int j = 0; j < 4; ++j)
            orow[dt * 16 + g * 4 + j] = f2bf(oacc[dt][j] * inv);
}

// ---------------------------------------------------------------------------
extern "C" void kernel_launch(void* const* d_in, const int* in_sizes, int n_in,
                              void* d_out, int out_size, void* d_ws, size_t ws_size,
                              hipStream_t stream) {
    const float* x  = (const float*)d_in[0];
    const float* Wq = (const float*)d_in[1];
    const float* bq = (const float*)d_in[2];
    const float* Wk = (const float*)d_in[3];
    const float* bk = (const float*)d_in[4];
    const float* Wv = (const float*)d_in[5];
    const float* bv = (const float*)d_in[6];
    const float* Wo = (const float*)d_in[7];
    const float* bo = (const float*)d_in[8];
    const int* srcb = (const int*)d_in[9];
    const int* tgtb = (const int*)d_in[10];

    unsigned short* wsu = (unsigned short*)d_ws;
    unsigned short* xbf   = wsu;                      // [0,        4194304)
    unsigned short* wqkv  = wsu + 4194304ull;         // [4194304,  7340032)
    unsigned short* wobf  = wsu + 7340032ull;         // [7340032,  8388608)
    unsigned short* qkvbf = wsu + 8388608ull;         // [8388608,  20971520) Q,K,V panes
    unsigned short* attbf = wsu + 25165824ull;        // [25165824, 29360128)

    // all 5 fp32->bf16 conversions in one dispatch
    hipLaunchKernelGGL(cvt_all, dim3(512, 5), dim3(256), 0, stream,
                       x, Wq, Wk, Wv, Wo,
                       xbf, wqkv, wqkv + 1048576ull, wqkv + 2097152ull, wobf);

    // fused QKV GEMM (which = blockIdx.x>>3), plain [m][n] outputs
    hipLaunchKernelGGL((gemm_bt<1, 128>), dim3(24, 32), dim3(256), 0, stream,
                       xbf, wqkv, bq, bk, bv, qkvbf, (float*)nullptr);

    // attention (V transposed in-kernel during LDS staging)
    hipLaunchKernelGGL(attn_mfma, dim3(32, 16, 2), dim3(256), 0, stream,
                       qkvbf, qkvbf + 4194304ull, qkvbf + 2ull * 4194304ull,
                       srcb, tgtb, attbf);

    // O projection -> fp32 d_out; BN=64 -> 512 wgs (2/CU)
    hipLaunchKernelGGL((gemm_bt<0, 64>), dim3(16, 32), dim3(256), 0, stream,
                       attbf, wobf, bo, bo, bo, (unsigned short*)nullptr, (float*)d_out);

    (void)in_sizes; (void)n_in; (void)out_size; (void)ws_size;
}